// Round 20
// baseline (444.717 us; speedup 1.0000x reference)
//
#include <hip/hip_runtime.h>
#include <hip/hip_bf16.h>

#define DEV __device__ __forceinline__

typedef unsigned short u16;
typedef __attribute__((ext_vector_type(8))) short short8;
typedef __attribute__((ext_vector_type(4))) float float4v;

DEV u16 f2bf(float v) {
    __hip_bfloat16 h = __float2bfloat16(v);
    return *reinterpret_cast<u16*>(&h);
}
DEV float bf2f(u16 u) { return __uint_as_float(((unsigned)u) << 16); }

DEV float4v mfma16(short8 a, short8 b, float4v c) {
    return __builtin_amdgcn_mfma_f32_16x16x32_bf16(a, b, c, 0, 0, 0);
}

// async global->LDS, 16B per lane; LDS dest = wave-uniform base + lane*16.
DEV void gload_lds16(const u16* g, u16* l) {
    __builtin_amdgcn_global_load_lds(
        (const __attribute__((address_space(1))) void*)g,
        (__attribute__((address_space(3))) void*)l, 16, 0, 0);
}

// ---------------------------------------------------------------------------
// MFMA conv, 2-phase pipelined via global_load_lds (structure unchanged).
// KSPLIT=2: blockIdx.z = b*2+half; partials summed by inorm_stats/pack32.
// MF>1 only where grid stays >= 2 blocks/CU.
// ---------------------------------------------------------------------------
template <int K, bool UP, bool REFLECT, int NWO, int LGTW, int TH, int ACT = 0,
          int MF = 1, int KSPLIT = 1>
__global__ __launch_bounds__(256) void mconv(
    const u16* __restrict__ X0, int c0ch,
    const u16* __restrict__ X1, int nch,
    const u16* __restrict__ WT, int NOB,
    const float* __restrict__ bias, float* __restrict__ out,
    int OC, int W, int H, int tilesX, int SW,
    float* __restrict__ outB = nullptr)
{
    constexpr int P    = (K - 1) / 2;
    constexpr int K2   = K * K;
    constexpr int NWP  = 4 / NWO;
    constexpr int TW   = 1 << LGTW;
    constexpr int LW   = TW + K - 1;
    constexpr int ROWS = TH + K - 1;
    constexpr int IT   = ROWS * LW;          // live 16B slots per icg
    constexpr int ITP  = IT | 1;             // padded (odd) slots per icg
    constexpr int ITEMS = ITP * 4;
    constexpr int CEIL = (ITEMS + 255) / 256;
    constexpr int BUF  = CEIL * 2048;        // u16 per buffer

    extern __shared__ u16 Xs[];
    const int tid = threadIdx.x;
    const int wv = tid >> 6, lane = tid & 63, lm = lane & 15, lg = lane >> 4;
    const int wo = wv / NWP, wp = wv % NWP;
    const int bx = blockIdx.x;
    const int bz = blockIdx.z;
    const int b    = (KSPLIT == 1) ? bz : (bz >> 1);
    const int half = (KSPLIT == 1) ? 0 : (bz & 1);
    const int ty = bx / tilesX, tx = bx - ty * tilesX;
    const int row0 = ty * TH, col0 = tx * TW;
    const int SH  = UP ? (H >> 1) : H;
    const int HWs = SW * SH;
    const int obBase = blockIdx.y * (NWO * MF) + wo * MF;
    const int wbase = tid & 192;             // wave-uniform slot base
    const int ch0 = half * (nch / KSPLIT);
    const int ch1 = ch0 + nch / KSPLIT;

    // ---- per-item source offsets (u16 units in channel plane), ch-invariant
    int offr[CEIL];
#pragma unroll
    for (int i = 0; i < CEIL; ++i) {
        int q = i * 256 + tid;
        bool bad = q >= ITEMS;
        if (bad) q = 0;
        int icg = q / ITP;
        int t   = q - icg * ITP;
        bad |= (t >= IT);                    // pad slot: never loaded/read
        int tr  = t / LW, tc = t - tr * LW;
        int gy = row0 - P + tr, gx = col0 - P + tc;
        if (REFLECT) {
            gy = gy < 0 ? -gy : (gy >= H ? 2 * H - 2 - gy : gy);
            gx = gx < 0 ? -gx : (gx >= W ? 2 * W - 2 - gx : gx);
            int sy = UP ? (gy >> 1) : gy, sx = UP ? (gx >> 1) : gx;
            offr[i] = bad ? -1 : (sy * SW + sx) * 32 + icg * 8;
        } else {
            bool ok = (gy >= 0) & (gy < H) & (gx >= 0) & (gx < W) & !bad;
            int sy = UP ? (gy >> 1) : gy, sx = UP ? (gx >> 1) : gx;
            offr[i] = ok ? (sy * SW + sx) * 32 + icg * 8 : -1;
        }
    }

    // ---- per-nf bases: LDS read offset (u16) and output pixel
    int rb16[4], opx[4];
#pragma unroll
    for (int nf = 0; nf < 4; ++nf) {
        int pt = wp * 64 + nf * 16 + lm;
        int ro = pt >> LGTW, co = pt & (TW - 1);
        rb16[nf] = (lg * ITP + ro * LW + co) * 8;
        opx[nf]  = (row0 + ro) * W + col0 + co;
    }

    float4v acc[MF][4];
#pragma unroll
    for (int m = 0; m < MF; ++m)
#pragma unroll
        for (int n = 0; n < 4; ++n) acc[m][n] = (float4v){0.f, 0.f, 0.f, 0.f};

    auto planeptr = [&](int ch) -> const u16* {
        return (ch < c0ch)
            ? X0 + (size_t)(b * c0ch + ch) * HWs * 32
            : X1 + (size_t)(b * (nch - c0ch) + (ch - c0ch)) * HWs * 32;
    };

    // zero both buffers once (zero-pad convs only; OOB set is chunk-invariant)
    if (!REFLECT) {
        const uint4 UZ = {0u, 0u, 0u, 0u};
        for (int i = tid; i < BUF / 4; i += 256)
            *(uint4*)(Xs + (size_t)i * 8) = UZ;
        __syncthreads();
    }

    // ---- prologue: async-load first chunk into buf 0 ----
    {
        const u16* src = planeptr(ch0);
#pragma unroll
        for (int i = 0; i < CEIL; ++i)
            if (offr[i] >= 0)
                gload_lds16(src + offr[i], &Xs[(size_t)(i * 256 + wbase) * 8]);
    }
    __syncthreads();

    int cur = 0;
    for (int ch = ch0; ch < ch1; ++ch) {
        if (ch + 1 < ch1) {
            const u16* src = planeptr(ch + 1);
            u16* dstb = Xs + (size_t)(cur ^ 1) * BUF;
#pragma unroll
            for (int i = 0; i < CEIL; ++i)
                if (offr[i] >= 0)
                    gload_lds16(src + offr[i], &dstb[(size_t)(i * 256 + wbase) * 8]);
        }
        const u16* base = Xs + (size_t)cur * BUF;
        const u16* wch  = WT + ((size_t)ch * NOB + obBase) * K2 * 512 + lane * 8;
#pragma unroll
        for (int ky = 0; ky < K; ++ky) {
#pragma unroll
            for (int kx = 0; kx < K; ++kx) {
                const int tap = ky * K + kx;
                short8 Bf[4];
#pragma unroll
                for (int nf = 0; nf < 4; ++nf)
                    Bf[nf] = *(const short8*)(base + rb16[nf] + (ky * LW + kx) * 8);
#pragma unroll
                for (int m = 0; m < MF; ++m) {
                    short8 Af = *(const short8*)(wch + ((size_t)m * K2 + tap) * 512);
#pragma unroll
                    for (int nf = 0; nf < 4; ++nf)
                        acc[m][nf] = mfma16(Af, Bf[nf], acc[m][nf]);
                }
            }
        }
        __syncthreads();
        cur ^= 1;
    }

    // ---- epilogue ----
    const size_t HWo = (size_t)H * W;
    float* dst = (KSPLIT == 2 && half) ? outB : out;
#pragma unroll
    for (int m = 0; m < MF; ++m) {
        int oc0 = (obBase + m) * 16 + lg * 4;
#pragma unroll
        for (int nf = 0; nf < 4; ++nf) {
#pragma unroll
            for (int r = 0; r < 4; ++r) {
                int oc = oc0 + r;
                if (oc < OC) {
                    float bv = (KSPLIT == 2 && half) ? 0.f : bias[oc];
                    float v = acc[m][nf][r] + bv;
                    if (ACT == 2) v = tanhf(v);
                    dst[(size_t)(b * OC + oc) * HWo + opx[nf]] = v;
                }
            }
        }
    }
}

// ---------------------------------------------------------------------------
// Weight pack: w[OC][IC][K2] fp32 -> wt[ch][ob][tap][lane][8] bf16 (A-frag).
// ---------------------------------------------------------------------------
DEV void wpack_one(const float* w, u16* wt, int OC, int IC, int K2, int NOB, int i)
{
    int e = i & 7;
    int l = (i >> 3) & 63;
    int rest = i >> 9;
    int tap = rest % K2;
    rest /= K2;
    int ob = rest % NOB;
    int ch = rest / NOB;
    int oc = ob * 16 + (l & 15);
    if (oc >= OC) oc = OC - 1;
    int ic = ch * 32 + (l >> 4) * 8 + e;
    wt[i] = f2bf(w[((size_t)oc * IC + ic) * K2 + tap]);
}

// Batched pack: ALL 9 conv weight tensors in one upfront launch.
struct WSegs {
    const float* w[9];
    u16* dst[9];
    int OC[9], IC[9], K2[9], NOB[9], total[9];
};
__global__ __launch_bounds__(256) void wpack_batch(WSegs s)
{
    int g = blockIdx.y;
    int i = blockIdx.x * 256 + threadIdx.x;
    if (i >= s.total[g]) return;
    wpack_one(s.w[g], s.dst[g], s.OC[g], s.IC[g], s.K2[g], s.NOB[g], i);
}

// Deform weight pack: w[O][C][9] fp32 -> dwt[k][ob][cc][lane][8] bf16.
template <int C, int O>
__global__ __launch_bounds__(256) void dwtrans(
    const float* __restrict__ w, u16* __restrict__ dwt)
{
    constexpr int NOB = O / 16, NCC = C / 32;
    constexpr int total = 9 * NOB * NCC * 512;
    int i = blockIdx.x * 256 + threadIdx.x;
    if (i >= total) return;
    int e = i & 7;
    int l = (i >> 3) & 63;
    int rest = i >> 9;
    int cc = rest % NCC;
    rest /= NCC;
    int ob = rest % NOB;
    int k  = rest / NOB;
    int oc = ob * 16 + (l & 15);
    int ic = cc * 32 + (l >> 4) * 8 + e;
    dwt[i] = f2bf(w[((size_t)oc * C + ic) * 9 + k]);
}

// ---------------------------------------------------------------------------
// pack32: fp32 NCHW (optionally x+x2 partial sum) -> bf16 chunked
// [b][chunk][px][32c] with coalesced 64B stores. LGPX=6 for small-HW layers.
// MODE: 0 = plain cast, 1 = inorm+relu, 2 = inorm+residual.
// ---------------------------------------------------------------------------
template <int MODE, bool WF32, bool ADD2 = false, int LGPX = 8>
__global__ __launch_bounds__(256) void pack32(
    const float* __restrict__ x, const float* __restrict__ x2,
    float* __restrict__ xout,
    const float* __restrict__ stats, const float* __restrict__ res,
    u16* __restrict__ tout, int lgHW, int lgC)
{
    constexpr int PX  = 1 << LGPX;
    constexpr int CG  = 256 / PX;       // channel-groups per px
    constexpr int CPT = 32 / CG;        // channels per thread
    constexpr int GW  = 4 / CG;         // uint4 writes per thread
    __shared__ float tile[32][PX + 1];
    const int t   = threadIdx.x;
    const int pxl = t & (PX - 1);
    const int grp = t >> LGPX;
    const int px  = blockIdx.x * PX + pxl;
    const int c0  = blockIdx.y * 32;
    const int b   = blockIdx.z;
    const int C   = 1 << lgC;

#pragma unroll
    for (int j = 0; j < CPT; ++j) {
        int c = grp * CPT + j;
        int bc = (b << lgC) + c0 + c;
        size_t idx = ((size_t)bc << lgHW) + px;
        float v = x[idx];
        if (ADD2) v += x2[idx];
        if (MODE) {
            float m = stats[2 * bc], r = stats[2 * bc + 1];
            v = (v - m) * r;
            if (MODE == 1) v = fmaxf(v, 0.f);
            if (MODE == 2) v += res[idx];
        }
        if (WF32) xout[idx] = v;
        tile[c][pxl] = v;
    }
    __syncthreads();

    size_t o = ((((size_t)(b * (C >> 5) + (c0 >> 5)) << lgHW) + px) << 5);
#pragma unroll
    for (int g2 = 0; g2 < GW; ++g2) {
        int g = grp * GW + g2;
        u16 tmp[8];
#pragma unroll
        for (int j = 0; j < 8; ++j)
            tmp[j] = f2bf(tile[g * 8 + j][pxl]);
        *(uint4*)(tout + o + g * 8) = *(const uint4*)tmp;
    }
}

// ---------------------- instance norm stats (x or x+x2) --------------------
__global__ __launch_bounds__(256) void inorm_stats(
    const float* __restrict__ x, const float* __restrict__ x2,
    float* __restrict__ stats, int HW)
{
    __shared__ float sh[8];
    const int bc = blockIdx.x;
    const float* p  = x + (size_t)bc * HW;
    const float* p2 = x2 ? x2 + (size_t)bc * HW : nullptr;
    float s = 0.f, ss = 0.f;
    for (int i = threadIdx.x; i < HW; i += 256) {
        float v = p[i];
        if (p2) v += p2[i];
        s += v; ss = fmaf(v, v, ss);
    }
#pragma unroll
    for (int o = 32; o; o >>= 1) { s += __shfl_down(s, o); ss += __shfl_down(ss, o); }
    if ((threadIdx.x & 63) == 0) {
        sh[(threadIdx.x >> 6) * 2] = s;
        sh[(threadIdx.x >> 6) * 2 + 1] = ss;
    }
    __syncthreads();
    if (threadIdx.x == 0) {
        s  = sh[0] + sh[2] + sh[4] + sh[6];
        ss = sh[1] + sh[3] + sh[5] + sh[7];
        float m   = s / HW;
        float var = ss / HW - m * m;
        stats[2 * bc]     = m;
        stats[2 * bc + 1] = rsqrtf(var + 1e-5f);
    }
}

// ---------------------------------------------------------------------------
// MFMA deformable conv — 256-thread variant (deform1).
// ---------------------------------------------------------------------------
template <int C, int O, int MF>
__global__ __launch_bounds__(256) void deform_mfma(
    const u16* __restrict__ featT, const float* __restrict__ om,
    const u16* __restrict__ dwt, const float* __restrict__ bias,
    u16* __restrict__ outT, int H, int W, int lgW)
{
    constexpr int NOB = O / 16, NCC = C / 32;
    constexpr int NT = 576;
    constexpr int CPT = C / 4;
    const int HW = H * W;
    const int b  = blockIdx.y;
    const int p0 = blockIdx.x * 64;
    const int tid = threadIdx.x;
    const int wv = tid >> 6, lane = tid & 63, lm = lane & 15, lg = lane >> 4;

    __shared__ int   sO[4][NT];
    __shared__ float sW[4][NT];
    __shared__ u16   val[64 * C];

    for (int t = tid; t < NT; t += 256) {
        int px = t & 63, k = t >> 6;
        int p  = p0 + px;
        int hh = p >> lgW, ww = p & (W - 1);
        float dy = om[((size_t)b * 27 + k) * HW + p];
        float dx = om[((size_t)b * 27 + 9 + k) * HW + p];
        float mk = 1.f / (1.f + __expf(-om[((size_t)b * 27 + 18 + k) * HW + p]));
        float py  = (float)(hh + k / 3 - 1) + dy;
        float pxf = (float)(ww + k % 3 - 1) + dx;
        float y0f = floorf(py), x0f = floorf(pxf);
        int y0 = (int)y0f, x0 = (int)x0f;
        float wy = py - y0f, wx = pxf - x0f;
        float vy0 = ((unsigned)y0       < (unsigned)H) ? 1.f : 0.f;
        float vy1 = ((unsigned)(y0 + 1) < (unsigned)H) ? 1.f : 0.f;
        float vx0 = ((unsigned)x0       < (unsigned)W) ? 1.f : 0.f;
        float vx1 = ((unsigned)(x0 + 1) < (unsigned)W) ? 1.f : 0.f;
        int y0c = min(max(y0, 0), H - 1), y1c = min(max(y0 + 1, 0), H - 1);
        int x0c = min(max(x0, 0), W - 1), x1c = min(max(x0 + 1, 0), W - 1);
        sO[0][t] = y0c * W + x0c;  sO[1][t] = y0c * W + x1c;
        sO[2][t] = y1c * W + x0c;  sO[3][t] = y1c * W + x1c;
        sW[0][t] = (1.f - wy) * (1.f - wx) * vy0 * vx0 * mk;
        sW[1][t] = (1.f - wy) * wx         * vy0 * vx1 * mk;
        sW[2][t] = wy         * (1.f - wx) * vy1 * vx0 * mk;
        sW[3][t] = wy         * wx         * vy1 * vx1 * mk;
    }
    __syncthreads();

    float4v acc[MF][4];
#pragma unroll
    for (int m = 0; m < MF; ++m)
#pragma unroll
        for (int n = 0; n < 4; ++n) acc[m][n] = (float4v){0.f, 0.f, 0.f, 0.f};

    const int gpx = tid >> 2, gc0 = (tid & 3) * CPT;

    for (int k = 0; k < 9; ++k) {
        if (k) __syncthreads();
        {
            int t = k * 64 + gpx;
            int o0 = sO[0][t], o1 = sO[1][t], o2 = sO[2][t], o3 = sO[3][t];
            float w0 = sW[0][t], w1 = sW[1][t], w2 = sW[2][t], w3 = sW[3][t];
#pragma unroll
            for (int c8 = 0; c8 < CPT / 8; ++c8) {
                int c = gc0 + c8 * 8;
                const u16* base = featT + ((size_t)(b * NCC + (c >> 5)) * HW) * 32 + (c & 31);
                uint4 r0 = *(const uint4*)(base + (size_t)o0 * 32);
                uint4 r1 = *(const uint4*)(base + (size_t)o1 * 32);
                uint4 r2 = *(const uint4*)(base + (size_t)o2 * 32);
                uint4 r3 = *(const uint4*)(base + (size_t)o3 * 32);
                const u16* p0_ = (const u16*)&r0;
                const u16* p1_ = (const u16*)&r1;
                const u16* p2_ = (const u16*)&r2;
                const u16* p3_ = (const u16*)&r3;
                u16 outv[8];
#pragma unroll
                for (int j = 0; j < 8; ++j) {
                    float s = w0 * bf2f(p0_[j]) + w1 * bf2f(p1_[j])
                            + w2 * bf2f(p2_[j]) + w3 * bf2f(p3_[j]);
                    outv[j] = f2bf(s);
                }
                int csw = c ^ ((gpx & 7) << 3);
                *(uint4*)(val + gpx * C + csw) = *(uint4*)outv;
            }
        }
        __syncthreads();
        const u16* wk = dwt + (size_t)k * NOB * NCC * 512;
#pragma unroll
        for (int m = 0; m < MF; ++m) {
            int ob = wv * MF + m;
#pragma unroll
            for (int cc = 0; cc < NCC; ++cc) {
                short8 Af = *(const short8*)(wk + ((size_t)ob * NCC + cc) * 512 + lane * 8);
#pragma unroll
                for (int nf = 0; nf < 4; ++nf) {
                    int row = nf * 16 + lm;
                    int csw = (cc * 32 + lg * 8) ^ ((row & 7) << 3);
                    short8 Bf = *(const short8*)(val + row * C + csw);
                    acc[m][nf] = mfma16(Af, Bf, acc[m][nf]);
                }
            }
        }
    }

#pragma unroll
    for (int m = 0; m < MF; ++m) {
        int oc0 = (wv * MF + m) * 16 + lg * 4;
#pragma unroll
        for (int nf = 0; nf < 4; ++nf) {
            int p = p0 + nf * 16 + lm;
#pragma unroll
            for (int r = 0; r < 4; ++r) {
                int oc = oc0 + r;
                outT[((size_t)(b * (O / 32) + (oc >> 5)) * HW + p) * 32 + (oc & 31)]
                    = f2bf(acc[m][nf][r] + bias[oc]);
            }
        }
    }
}

// ---------------------------------------------------------------------------
// 512-thread deformable conv for deform2 (round-16 win).
// ---------------------------------------------------------------------------
template <int C, int O>
__global__ __launch_bounds__(512) void deform_mfma512(
    const u16* __restrict__ featT, const float* __restrict__ om,
    const u16* __restrict__ dwt, const float* __restrict__ bias,
    u16* __restrict__ outT, int H, int W, int lgW)
{
    constexpr int NOB = O / 16, NCC = C / 32;
    constexpr int NT = 576;
    constexpr int CPT = C / 8;
    const int HW = H * W;
    const int b  = blockIdx.y;
    const int p0 = blockIdx.x * 64;
    const int tid = threadIdx.x;
    const int wv = tid >> 6, lane = tid & 63, lm = lane & 15, lg = lane >> 4;

    __shared__ int   sO[4][NT];
    __shared__ float sW[4][NT];
    __shared__ u16   val[64 * C];

    for (int t = tid; t < NT; t += 512) {
        int px = t & 63, k = t >> 6;
        int p  = p0 + px;
        int hh = p >> lgW, ww = p & (W - 1);
        float dy = om[((size_t)b * 27 + k) * HW + p];
        float dx = om[((size_t)b * 27 + 9 + k) * HW + p];
        float mk = 1.f / (1.f + __expf(-om[((size_t)b * 27 + 18 + k) * HW + p]));
        float py  = (float)(hh + k / 3 - 1) + dy;
        float pxf = (float)(ww + k % 3 - 1) + dx;
        float y0f = floorf(py), x0f = floorf(pxf);
        int y0 = (int)y0f, x0 = (int)x0f;
        float wy = py - y0f, wx = pxf - x0f;
        float vy0 = ((unsigned)y0       < (unsigned)H) ? 1.f : 0.f;
        float vy1 = ((unsigned)(y0 + 1) < (unsigned)H) ? 1.f : 0.f;
        float vx0 = ((unsigned)x0       < (unsigned)W) ? 1.f : 0.f;
        float vx1 = ((unsigned)(x0 + 1) < (unsigned)W) ? 1.f : 0.f;
        int y0c = min(max(y0, 0), H - 1), y1c = min(max(y0 + 1, 0), H - 1);
        int x0c = min(max(x0, 0), W - 1), x1c = min(max(x0 + 1, 0), W - 1);
        sO[0][t] = y0c * W + x0c;  sO[1][t] = y0c * W + x1c;
        sO[2][t] = y1c * W + x0c;  sO[3][t] = y1c * W + x1c;
        sW[0][t] = (1.f - wy) * (1.f - wx) * vy0 * vx0 * mk;
        sW[1][t] = (1.f - wy) * wx         * vy0 * vx1 * mk;
        sW[2][t] = wy         * (1.f - wx) * vy1 * vx0 * mk;
        sW[3][t] = wy         * wx         * vy1 * vx1 * mk;
    }
    __syncthreads();

    float4v acc[4];
#pragma unroll
    for (int n = 0; n < 4; ++n) acc[n] = (float4v){0.f, 0.f, 0.f, 0.f};

    const int gpx = tid >> 3, gc0 = (tid & 7) * CPT;

    for (int k = 0; k < 9; ++k) {
        if (k) __syncthreads();
        {
            int t = k * 64 + gpx;
            int o0 = sO[0][t], o1 = sO[1][t], o2 = sO[2][t], o3 = sO[3][t];
            float w0 = sW[0][t], w1 = sW[1][t], w2 = sW[2][t], w3 = sW[3][t];
#pragma unroll
            for (int c8 = 0; c8 < CPT / 8; ++c8) {
                int c = gc0 + c8 * 8;
                const u16* base = featT + ((size_t)(b * NCC + (c >> 5)) * HW) * 32 + (c & 31);
                uint4 r0 = *(const uint4*)(base + (size_t)o0 * 32);
                uint4 r1 = *(const uint4*)(base + (size_t)o1 * 32);
                uint4 r2 = *(const uint4*)(base + (size_t)o2 * 32);
                uint4 r3 = *(const uint4*)(base + (size_t)o3 * 32);
                const u16* p0_ = (const u16*)&r0;
                const u16* p1_ = (const u16*)&r1;
                const u16* p2_ = (const u16*)&r2;
                const u16* p3_ = (const u16*)&r3;
                u16 outv[8];
#pragma unroll
                for (int j = 0; j < 8; ++j) {
                    float s = w0 * bf2f(p0_[j]) + w1 * bf2f(p1_[j])
                            + w2 * bf2f(p2_[j]) + w3 * bf2f(p3_[j]);
                    outv[j] = f2bf(s);
                }
                int csw = c ^ ((gpx & 7) << 3);
                *(uint4*)(val + gpx * C + csw) = *(uint4*)outv;
            }
        }
        __syncthreads();
        const u16* wk = dwt + (size_t)k * NOB * NCC * 512;
        const int ob = wv;
#pragma unroll
        for (int cc = 0; cc < NCC; ++cc) {
            short8 Af = *(const short8*)(wk + ((size_t)ob * NCC + cc) * 512 + lane * 8);
#pragma unroll
            for (int nf = 0; nf < 4; ++nf) {
                int row = nf * 16 + lm;
                int csw = (cc * 32 + lg * 8) ^ ((row & 7) << 3);
                short8 Bf = *(const short8*)(val + row * C + csw);
                acc[nf] = mfma16(Af, Bf, acc[nf]);
            }
        }
    }

    {
        int oc0 = wv * 16 + lg * 4;
#pragma unroll
        for (int nf = 0; nf < 4; ++nf) {
            int p = p0 + nf * 16 + lm;
#pragma unroll
            for (int r = 0; r < 4; ++r) {
                int oc = oc0 + r;
                outT[((size_t)(b * (O / 32) + (oc >> 5)) * HW + p) * 32 + (oc & 31)]
                    = f2bf(acc[nf][r] + bias[oc]);
            }
        }
    }
}

// ---------------------- offset |mean| reductions --------------------------
__global__ __launch_bounds__(256) void absmean_partial(
    const float* __restrict__ om, int HW, float* __restrict__ partial)
{
    const int n18 = 18 * HW;
    const long long total = 4LL * n18;
    float s = 0.f;
    for (long long i = (long long)blockIdx.x * 256 + threadIdx.x; i < total;
         i += (long long)gridDim.x * 256) {
        int b = (int)(i / n18);
        int r = (int)(i % n18);
        s += fabsf(om[(size_t)b * 27 * HW + r]);
    }
    __shared__ float sh[4];
#pragma unroll
    for (int o = 32; o; o >>= 1) s += __shfl_down(s, o);
    if ((threadIdx.x & 63) == 0) sh[threadIdx.x >> 6] = s;
    __syncthreads();
    if (threadIdx.x == 0) partial[blockIdx.x] = sh[0] + sh[1] + sh[2] + sh[3];
}

__global__ __launch_bounds__(256) void finalize_k(
    const float* __restrict__ p1, const float* __restrict__ p2,
    float* __restrict__ outScalar)
{
    __shared__ float sh[8];
    float a = p1[threadIdx.x] + p1[threadIdx.x + 256];
    float b = p2[threadIdx.x] + p2[threadIdx.x + 256];
#pragma unroll
    for (int o = 32; o; o >>= 1) { a += __shfl_down(a, o); b += __shfl_down(b, o); }
    if ((threadIdx.x & 63) == 0) {
        sh[(threadIdx.x >> 6) * 2]     = a;
        sh[(threadIdx.x >> 6) * 2 + 1] = b;
    }
    __syncthreads();
    if (threadIdx.x == 0) {
        a = sh[0] + sh[2] + sh[4] + sh[6];
        b = sh[1] + sh[3] + sh[5] + sh[7];
        *outScalar = 0.5f * (a / (4.f * 18.f * 16384.f) + b / (4.f * 18.f * 4096.f));
    }
}

// ---------------------------------------------------------------------------
extern "C" void kernel_launch(void* const* d_in, const int* in_sizes, int n_in,
                              void* d_out, int out_size, void* d_ws, size_t ws_size,
                              hipStream_t stream)
{
    const float* x      = (const float*)d_in[0];
    const float* skip1  = (const float*)d_in[1];
    const float* skip2  = (const float*)d_in[2];
    const float* rb1_w1 = (const float*)d_in[3];
    const float* rb1_b1 = (const float*)d_in[4];
    const float* rb1_w2 = (const float*)d_in[5];
    const float* rb1_b2 = (const float*)d_in[6];
    const float* rb2_w1 = (const float*)d_in[7];
    const float* rb2_b1 = (const float*)d_in[8];
    const float* rb2_w2 = (const float*)d_in[9];
    const float* rb2_b2 = (const float*)d_in[10];
    const float* c1_w   = (const float*)d_in[11];
    const float* c1_b   = (const float*)d_in[12];
    const float* c2_w   = (const float*)d_in[13];
    const float* c2_b   = (const float*)d_in[14];
    const float* c3_w   = (const float*)d_in[15];
    const float* c3_b   = (const float*)d_in[16];
    const float* off2_w = (const float*)d_in[17];
    const float* off2_b = (const float*)d_in[18];
    const float* d2_w   = (const float*)d_in[19];
    const float* d2_b   = (const float*)d_in[20];
    const float* off1_w = (const float*)d_in[21];
    const float* off1_b = (const float*)d_in[22];
    const float* d1_w   = (const float*)d_in[23];
    const float* d1_b   = (const float*)d_in[24];

    float* ws    = (float*)d_ws;
    float* stats = ws;
    float* part2 = ws + 2048;
    float* part1 = ws + 2560;

    // ---- weight pack arenas (words) ----
    u16* wtRB1 = (u16*)(ws + 4096);
    u16* wtC1 = (u16*)(ws + 299008);
    u16* wtC2 = (u16*)(ws + 708608);
    u16* wtO2 = (u16*)(ws + 913408);
    u16* wtO1 = (u16*)(ws + 950272);
    u16* wtC3 = (u16*)(ws + 968704);
    // ---- Z1 @1018880: R2 fp32 (4M w) with early overlays ----
    float* R2  = ws + 1018880;                 // [c2 -> pack32]
    u16*  xT   = (u16*)(ws + 1018880);
    u16*  A1T  = xT;
    u16*  A2T  = (u16*)(ws + 1018880 + 524288);
    u16*  A3T  = A2T;
    float* A1  = ws + 1018880 + 1048576;
    float* A2  = ws + 1018880 + 2097152;
    float* A3  = ws + 1018880 + 3145728;       // rb K-split partial (PB)
    float* OM2 = ws + 1018880;                 // [off2 -> deform2/absmean]
    u16*  CP1T = (u16*)(ws + 1018880);         // [deform1 -> c3] (OM2/R2 dead)
    float* PBC1 = ws + 1018880 + 1048576;      // c1 K-split partial (A1+A2 zones)
    // ---- Z2: s1T @5213184 ----
    u16*  s1T  = (u16*)(ws + 5213184);         // [-> deform1]
    // ---- Z3 @7310336 (2M w): rb2-4 weight arenas UPFRONT, dead before c1
    u16*  wtRB2 = (u16*)(ws + 7310336);        // 294912 w [upfront -> rb1c2]
    u16*  wtRB3 = (u16*)(ws + 7605248);        // 294912 w [upfront -> rb2c1]
    u16*  wtRB4 = (u16*)(ws + 7900160);        // 294912 w [upfront -> rb2c2]
    float* R1  = ws + 7310336;                 // [c1 -> pack32]
    u16*  CP2T = (u16*)(ws + 7384064);         // [deform2 -> c2]
    u16*  R2T  = (u16*)(ws + 7310336);         // [pack32(after c2) -> off1, c3]
    // ---- Z4 @9407488: R1T then OM1 ----
    u16*  R1T  = (u16*)(ws + 9407488);         // [-> c2]
    float* OM1 = ws + 9407488;                 // [off1 -> deform1/absmean]
    // ---- Z5: s2T @10456064 (ends 11504640) ----
    u16*  s2T  = (u16*)(ws + 10456064);        // [-> deform2]
    // ---- tail @11504640: deform weight arenas, upfront.
    //      wtD2: 147456 u16 = 73728 words (round-19 bug: was sized 36864 —
    //      u16 count vs float words — so wtD1 sat inside wtD2 and the d1
    //      pack clobbered d2's weights). End 11596800 w = 46.4 MB.
    u16*  wtD2 = (u16*)(ws + 11504640);        // 73728 w [upfront -> deform2]
    u16*  wtD1 = (u16*)(ws + 11578368);        // 18432 w [upfront -> deform1]

    float* outp = (float*)d_out;
    dim3 blk(256);

    // ---- batched weight packs + deform packs: all upfront ----
    WSegs segs;
    segs.w[0] = c1_w;   segs.dst[0] = wtC1;  segs.OC[0] = 128; segs.IC[0] = 256; segs.K2[0] = 25; segs.NOB[0] = 8;  segs.total[0] = 819200;
    segs.w[1] = c2_w;   segs.dst[1] = wtC2;  segs.OC[1] = 64;  segs.IC[1] = 256; segs.K2[1] = 25; segs.NOB[1] = 4;  segs.total[1] = 409600;
    segs.w[2] = off2_w; segs.dst[2] = wtO2;  segs.OC[2] = 27;  segs.IC[2] = 256; segs.K2[2] = 9;  segs.NOB[2] = 2;  segs.total[2] = 73728;
    segs.w[3] = off1_w; segs.dst[3] = wtO1;  segs.OC[3] = 27;  segs.IC[3] = 128; segs.K2[3] = 9;  segs.NOB[3] = 2;  segs.total[3] = 36864;
    segs.w[4] = c3_w;   segs.dst[4] = wtC3;  segs.OC[4] = 3;   segs.IC[4] = 128; segs.K2[4] = 49; segs.NOB[4] = 1;  segs.total[4] = 100352;
    segs.w[5] = rb1_w1; segs.dst[5] = wtRB1; segs.OC[5] = 256; segs.IC[5] = 256; segs.K2[5] = 9;  segs.NOB[5] = 16; segs.total[5] = 589824;
    segs.w[6] = rb1_w2; segs.dst[6] = wtRB2; segs.OC[6] = 256; segs.IC[6] = 256; segs.K2[6] = 9;  segs.NOB[6] = 16; segs.total[6] = 589824;
    segs.w[7] = rb2_w1; segs.dst[7] = wtRB3; segs.OC[7] = 256; segs.IC[7] = 256; segs.K2[7] = 9;  segs.NOB[7] = 16; segs.total[7] = 589824;
    segs.w[8] = rb2_w2; segs.dst[8] = wtRB4; segs.OC[8] = 256; segs.IC[8] = 256; segs.K2[8] = 9;  segs.NOB[8] = 16; segs.total[8] = 589824;
    wpack_batch<<<dim3(3200, 9), blk, 0, stream>>>(segs);
    dwtrans<128, 128><<<576, blk, 0, stream>>>(d2_w, wtD2);
    dwtrans<64, 64><<<144, blk, 0, stream>>>(d1_w, wtD1);

    // ---- input transforms ----
    pack32<0, false, false, 6><<<dim3(16, 8, 4), blk, 0, stream>>>(x, nullptr, nullptr, nullptr, nullptr, xT, 10, 8);
    pack32<0, false><<<dim3(64, 2, 4), blk, 0, stream>>>(skip1, nullptr, nullptr, nullptr, nullptr, s1T, 14, 6);
    pack32<0, false, false, 6><<<dim3(64, 4, 4), blk, 0, stream>>>(skip2, nullptr, nullptr, nullptr, nullptr, s2T, 12, 7);

    // ---- resblock 1 conv 1 (KSPLIT=2: PA=A1+bias, PB=A3) ----
    mconv<3, false, true, 2, 5, 4, 0, 1, 2><<<dim3(8, 8, 8), blk, 32768, stream>>>(
        xT, 8, nullptr, 8, wtRB1, 16, rb1_b1, A1, 256, 32, 32, 1, 32, A3);
    inorm_stats<<<1024, blk, 0, stream>>>(A1, A3, stats, 1024);
    pack32<1, false, true, 6><<<dim3(16, 8, 4), blk, 0, stream>>>(A1, A3, nullptr, stats, nullptr, A1T, 10, 8);
    // ---- resblock 1 conv 2 ----
    mconv<3, false, true, 2, 5, 4, 0, 1, 2><<<dim3(8, 8, 8), blk, 32768, stream>>>(
        A1T, 8, nullptr, 8, wtRB2, 16, rb1_b2, A2, 256, 32, 32, 1, 32, A3);
    inorm_stats<<<1024, blk, 0, stream>>>(A2, A3, stats, 1024);
    pack32<2, true, true, 6><<<dim3(16, 8, 4), blk, 0, stream>>>(A2, A3, A2, stats, x, A2T, 10, 8);
    // ---- resblock 2 conv 1 ----
    mconv<3, false, true, 2, 5, 4, 0, 1, 2><<<dim3(8, 8, 8), blk, 32768, stream>>>(
        A2T, 8, nullptr, 8, wtRB3, 16, rb2_b1, A1, 256, 32, 32, 1, 32, A3);
    inorm_stats<<<1024, blk, 0, stream>>>(A1, A3, stats, 1024);
    pack32<1, false, true, 6><<<dim3(16, 8, 4), blk, 0, stream>>>(A1, A3, nullptr, stats, nullptr, A1T, 10, 8);
    // ---- resblock 2 conv 2 ----
    mconv<3, false, true, 2, 5, 4, 0, 1, 2><<<dim3(8, 8, 8), blk, 32768, stream>>>(
        A1T, 8, nullptr, 8, wtRB4, 16, rb2_b2, A3, 256, 32, 32, 1, 32, A1);
    inorm_stats<<<1024, blk, 0, stream>>>(A3, A1, stats, 1024);
    pack32<2, false, true, 6><<<dim3(16, 8, 4), blk, 0, stream>>>(A3, A1, nullptr, stats, A2, A3T, 10, 8);
    // ---- c1: up2 + 5x5 reflect, 256->128 @64 (MF=2 + KSPLIT=2) ----
    mconv<5, true, true, 2, 6, 2, 0, 2, 2><<<dim3(32, 2, 8), blk, 57344, stream>>>(
        A3T, 8, nullptr, 8, wtC1, 8, c1_b, R1, 128, 64, 64, 1, 32, PBC1);
    inorm_stats<<<512, blk, 0, stream>>>(R1, PBC1, stats, 4096);
    pack32<1, false, true, 6><<<dim3(64, 4, 4), blk, 0, stream>>>(R1, PBC1, nullptr, stats, nullptr, R1T, 12, 7);
    // ---- off2 -> deform2 immediately (absmean deferred off critical path) --
    mconv<3, false, false, 2, 6, 2><<<dim3(32, 1, 4), blk, 40960, stream>>>(
        R1T, 4, s2T, 8, wtO2, 2, off2_b, OM2, 27, 64, 64, 1, 64);
    deform_mfma512<128, 128><<<dim3(64, 4), dim3(512), 0, stream>>>(
        s2T, OM2, wtD2, d2_b, CP2T, 64, 64, 6);
    absmean_partial<<<512, blk, 0, stream>>>(OM2, 4096, part2);
    // ---- c2: up2(concat(CP2T, R1T)) + 5x5 reflect (round-11 proven) ----
    mconv<5, true, true, 2, 6, 2, 0, 2><<<dim3(128, 1, 4), blk, 57344, stream>>>(
        CP2T, 4, R1T, 8, wtC2, 4, c2_b, R2, 64, 128, 128, 2, 64);
    inorm_stats<<<256, blk, 0, stream>>>(R2, nullptr, stats, 16384);
    pack32<1, false><<<dim3(64, 2, 4), blk, 0, stream>>>(R2, nullptr, nullptr, stats, nullptr, R2T, 14, 6);
    // ---- off1 -> deform1 immediately ----
    mconv<3, false, false, 2, 6, 2><<<dim3(128, 1, 4), blk, 40960, stream>>>(
        R2T, 2, s1T, 4, wtO1, 2, off1_b, OM1, 27, 128, 128, 2, 128);
    deform_mfma<64, 64, 1><<<dim3(256, 4), blk, 0, stream>>>(
        s1T, OM1, wtD1, d1_b, CP1T, 128, 128, 7);
    absmean_partial<<<512, blk, 0, stream>>>(OM1, 16384, part1);
    // ---- c3: concat(CP1T, R2T) 7x7 reflect + tanh -> 3ch via MFMA ----
    mconv<7, false, true, 1, 4, 16, 2><<<dim3(64, 1, 4), blk, 65536, stream>>>(
        CP1T, 2, R2T, 4, wtC3, 1, c3_b, outp, 3, 128, 128, 8, 128);
    // ---- offset_sum ----
    finalize_k<<<1, blk, 0, stream>>>(part1, part2, outp + 196608);
}

// Round 21
// 414.650 us; speedup vs baseline: 1.0725x; 1.0725x over previous
//
#include <hip/hip_runtime.h>
#include <hip/hip_bf16.h>

#define DEV __device__ __forceinline__

typedef unsigned short u16;
typedef __attribute__((ext_vector_type(8))) short short8;
typedef __attribute__((ext_vector_type(4))) float float4v;

DEV u16 f2bf(float v) {
    __hip_bfloat16 h = __float2bfloat16(v);
    return *reinterpret_cast<u16*>(&h);
}
DEV float bf2f(u16 u) { return __uint_as_float(((unsigned)u) << 16); }

DEV float4v mfma16(short8 a, short8 b, float4v c) {
    return __builtin_amdgcn_mfma_f32_16x16x32_bf16(a, b, c, 0, 0, 0);
}

// async global->LDS, 16B per lane; LDS dest = wave-uniform base + lane*16.
DEV void gload_lds16(const u16* g, u16* l) {
    __builtin_amdgcn_global_load_lds(
        (const __attribute__((address_space(1))) void*)g,
        (__attribute__((address_space(3))) void*)l, 16, 0, 0);
}

// ---------------------------------------------------------------------------
// MFMA conv, 2-phase pipelined via global_load_lds (structure unchanged).
// KSPLIT=2: blockIdx.z = b*2+half; partials summed by inorm_stats/pack32
// (or combine_tanh for c3). MF>1 only where grid stays >= 2 blocks/CU.
// ---------------------------------------------------------------------------
template <int K, bool UP, bool REFLECT, int NWO, int LGTW, int TH, int ACT = 0,
          int MF = 1, int KSPLIT = 1>
__global__ __launch_bounds__(256) void mconv(
    const u16* __restrict__ X0, int c0ch,
    const u16* __restrict__ X1, int nch,
    const u16* __restrict__ WT, int NOB,
    const float* __restrict__ bias, float* __restrict__ out,
    int OC, int W, int H, int tilesX, int SW,
    float* __restrict__ outB = nullptr)
{
    constexpr int P    = (K - 1) / 2;
    constexpr int K2   = K * K;
    constexpr int NWP  = 4 / NWO;
    constexpr int TW   = 1 << LGTW;
    constexpr int LW   = TW + K - 1;
    constexpr int ROWS = TH + K - 1;
    constexpr int IT   = ROWS * LW;          // live 16B slots per icg
    constexpr int ITP  = IT | 1;             // padded (odd) slots per icg
    constexpr int ITEMS = ITP * 4;
    constexpr int CEIL = (ITEMS + 255) / 256;
    constexpr int BUF  = CEIL * 2048;        // u16 per buffer

    extern __shared__ u16 Xs[];
    const int tid = threadIdx.x;
    const int wv = tid >> 6, lane = tid & 63, lm = lane & 15, lg = lane >> 4;
    const int wo = wv / NWP, wp = wv % NWP;
    const int bx = blockIdx.x;
    const int bz = blockIdx.z;
    const int b    = (KSPLIT == 1) ? bz : (bz >> 1);
    const int half = (KSPLIT == 1) ? 0 : (bz & 1);
    const int ty = bx / tilesX, tx = bx - ty * tilesX;
    const int row0 = ty * TH, col0 = tx * TW;
    const int SH  = UP ? (H >> 1) : H;
    const int HWs = SW * SH;
    const int obBase = blockIdx.y * (NWO * MF) + wo * MF;
    const int wbase = tid & 192;             // wave-uniform slot base
    const int ch0 = half * (nch / KSPLIT);
    const int ch1 = ch0 + nch / KSPLIT;

    // ---- per-item source offsets (u16 units in channel plane), ch-invariant
    int offr[CEIL];
#pragma unroll
    for (int i = 0; i < CEIL; ++i) {
        int q = i * 256 + tid;
        bool bad = q >= ITEMS;
        if (bad) q = 0;
        int icg = q / ITP;
        int t   = q - icg * ITP;
        bad |= (t >= IT);                    // pad slot: never loaded/read
        int tr  = t / LW, tc = t - tr * LW;
        int gy = row0 - P + tr, gx = col0 - P + tc;
        if (REFLECT) {
            gy = gy < 0 ? -gy : (gy >= H ? 2 * H - 2 - gy : gy);
            gx = gx < 0 ? -gx : (gx >= W ? 2 * W - 2 - gx : gx);
            int sy = UP ? (gy >> 1) : gy, sx = UP ? (gx >> 1) : gx;
            offr[i] = bad ? -1 : (sy * SW + sx) * 32 + icg * 8;
        } else {
            bool ok = (gy >= 0) & (gy < H) & (gx >= 0) & (gx < W) & !bad;
            int sy = UP ? (gy >> 1) : gy, sx = UP ? (gx >> 1) : gx;
            offr[i] = ok ? (sy * SW + sx) * 32 + icg * 8 : -1;
        }
    }

    // ---- per-nf bases: LDS read offset (u16) and output pixel
    int rb16[4], opx[4];
#pragma unroll
    for (int nf = 0; nf < 4; ++nf) {
        int pt = wp * 64 + nf * 16 + lm;
        int ro = pt >> LGTW, co = pt & (TW - 1);
        rb16[nf] = (lg * ITP + ro * LW + co) * 8;
        opx[nf]  = (row0 + ro) * W + col0 + co;
    }

    float4v acc[MF][4];
#pragma unroll
    for (int m = 0; m < MF; ++m)
#pragma unroll
        for (int n = 0; n < 4; ++n) acc[m][n] = (float4v){0.f, 0.f, 0.f, 0.f};

    auto planeptr = [&](int ch) -> const u16* {
        return (ch < c0ch)
            ? X0 + (size_t)(b * c0ch + ch) * HWs * 32
            : X1 + (size_t)(b * (nch - c0ch) + (ch - c0ch)) * HWs * 32;
    };

    // zero both buffers once (zero-pad convs only; OOB set is chunk-invariant)
    if (!REFLECT) {
        const uint4 UZ = {0u, 0u, 0u, 0u};
        for (int i = tid; i < BUF / 4; i += 256)
            *(uint4*)(Xs + (size_t)i * 8) = UZ;
        __syncthreads();
    }

    // ---- prologue: async-load first chunk into buf 0 ----
    {
        const u16* src = planeptr(ch0);
#pragma unroll
        for (int i = 0; i < CEIL; ++i)
            if (offr[i] >= 0)
                gload_lds16(src + offr[i], &Xs[(size_t)(i * 256 + wbase) * 8]);
    }
    __syncthreads();

    int cur = 0;
    for (int ch = ch0; ch < ch1; ++ch) {
        if (ch + 1 < ch1) {
            const u16* src = planeptr(ch + 1);
            u16* dstb = Xs + (size_t)(cur ^ 1) * BUF;
#pragma unroll
            for (int i = 0; i < CEIL; ++i)
                if (offr[i] >= 0)
                    gload_lds16(src + offr[i], &dstb[(size_t)(i * 256 + wbase) * 8]);
        }
        const u16* base = Xs + (size_t)cur * BUF;
        const u16* wch  = WT + ((size_t)ch * NOB + obBase) * K2 * 512 + lane * 8;
#pragma unroll
        for (int ky = 0; ky < K; ++ky) {
#pragma unroll
            for (int kx = 0; kx < K; ++kx) {
                const int tap = ky * K + kx;
                short8 Bf[4];
#pragma unroll
                for (int nf = 0; nf < 4; ++nf)
                    Bf[nf] = *(const short8*)(base + rb16[nf] + (ky * LW + kx) * 8);
#pragma unroll
                for (int m = 0; m < MF; ++m) {
                    short8 Af = *(const short8*)(wch + ((size_t)m * K2 + tap) * 512);
#pragma unroll
                    for (int nf = 0; nf < 4; ++nf)
                        acc[m][nf] = mfma16(Af, Bf[nf], acc[m][nf]);
                }
            }
        }
        __syncthreads();
        cur ^= 1;
    }

    // ---- epilogue ----
    const size_t HWo = (size_t)H * W;
    float* dst = (KSPLIT == 2 && half) ? outB : out;
#pragma unroll
    for (int m = 0; m < MF; ++m) {
        int oc0 = (obBase + m) * 16 + lg * 4;
#pragma unroll
        for (int nf = 0; nf < 4; ++nf) {
#pragma unroll
            for (int r = 0; r < 4; ++r) {
                int oc = oc0 + r;
                if (oc < OC) {
                    float bv = (KSPLIT == 2 && half) ? 0.f : bias[oc];
                    float v = acc[m][nf][r] + bv;
                    if (ACT == 2) v = tanhf(v);
                    dst[(size_t)(b * OC + oc) * HWo + opx[nf]] = v;
                }
            }
        }
    }
}

// ---------------------------------------------------------------------------
// Weight pack: w[OC][IC][K2] fp32 -> wt[ch][ob][tap][lane][8] bf16 (A-frag).
// ---------------------------------------------------------------------------
DEV void wpack_one(const float* w, u16* wt, int OC, int IC, int K2, int NOB, int i)
{
    int e = i & 7;
    int l = (i >> 3) & 63;
    int rest = i >> 9;
    int tap = rest % K2;
    rest /= K2;
    int ob = rest % NOB;
    int ch = rest / NOB;
    int oc = ob * 16 + (l & 15);
    if (oc >= OC) oc = OC - 1;
    int ic = ch * 32 + (l >> 4) * 8 + e;
    wt[i] = f2bf(w[((size_t)oc * IC + ic) * K2 + tap]);
}

// Batched pack: ALL 9 conv weight tensors in one upfront launch.
struct WSegs {
    const float* w[9];
    u16* dst[9];
    int OC[9], IC[9], K2[9], NOB[9], total[9];
};
__global__ __launch_bounds__(256) void wpack_batch(WSegs s)
{
    int g = blockIdx.y;
    int i = blockIdx.x * 256 + threadIdx.x;
    if (i >= s.total[g]) return;
    wpack_one(s.w[g], s.dst[g], s.OC[g], s.IC[g], s.K2[g], s.NOB[g], i);
}

// Deform weight pack: w[O][C][9] fp32 -> dwt[k][ob][cc][lane][8] bf16.
template <int C, int O>
__global__ __launch_bounds__(256) void dwtrans(
    const float* __restrict__ w, u16* __restrict__ dwt)
{
    constexpr int NOB = O / 16, NCC = C / 32;
    constexpr int total = 9 * NOB * NCC * 512;
    int i = blockIdx.x * 256 + threadIdx.x;
    if (i >= total) return;
    int e = i & 7;
    int l = (i >> 3) & 63;
    int rest = i >> 9;
    int cc = rest % NCC;
    rest /= NCC;
    int ob = rest % NOB;
    int k  = rest / NOB;
    int oc = ob * 16 + (l & 15);
    int ic = cc * 32 + (l >> 4) * 8 + e;
    dwt[i] = f2bf(w[((size_t)oc * C + ic) * 9 + k]);
}

// ---------------------------------------------------------------------------
// pack32: fp32 NCHW (optionally x+x2 partial sum) -> bf16 chunked
// [b][chunk][px][32c] with coalesced 64B stores. LGPX=6 for small-HW layers.
// MODE: 0 = plain cast, 1 = inorm+relu, 2 = inorm+residual.
// ---------------------------------------------------------------------------
template <int MODE, bool WF32, bool ADD2 = false, int LGPX = 8>
__global__ __launch_bounds__(256) void pack32(
    const float* __restrict__ x, const float* __restrict__ x2,
    float* __restrict__ xout,
    const float* __restrict__ stats, const float* __restrict__ res,
    u16* __restrict__ tout, int lgHW, int lgC)
{
    constexpr int PX  = 1 << LGPX;
    constexpr int CG  = 256 / PX;       // channel-groups per px
    constexpr int CPT = 32 / CG;        // channels per thread
    constexpr int GW  = 4 / CG;         // uint4 writes per thread
    __shared__ float tile[32][PX + 1];
    const int t   = threadIdx.x;
    const int pxl = t & (PX - 1);
    const int grp = t >> LGPX;
    const int px  = blockIdx.x * PX + pxl;
    const int c0  = blockIdx.y * 32;
    const int b   = blockIdx.z;
    const int C   = 1 << lgC;

#pragma unroll
    for (int j = 0; j < CPT; ++j) {
        int c = grp * CPT + j;
        int bc = (b << lgC) + c0 + c;
        size_t idx = ((size_t)bc << lgHW) + px;
        float v = x[idx];
        if (ADD2) v += x2[idx];
        if (MODE) {
            float m = stats[2 * bc], r = stats[2 * bc + 1];
            v = (v - m) * r;
            if (MODE == 1) v = fmaxf(v, 0.f);
            if (MODE == 2) v += res[idx];
        }
        if (WF32) xout[idx] = v;
        tile[c][pxl] = v;
    }
    __syncthreads();

    size_t o = ((((size_t)(b * (C >> 5) + (c0 >> 5)) << lgHW) + px) << 5);
#pragma unroll
    for (int g2 = 0; g2 < GW; ++g2) {
        int g = grp * GW + g2;
        u16 tmp[8];
#pragma unroll
        for (int j = 0; j < 8; ++j)
            tmp[j] = f2bf(tile[g * 8 + j][pxl]);
        *(uint4*)(tout + o + g * 8) = *(const uint4*)tmp;
    }
}

// ---------------------- instance norm stats (x or x+x2) --------------------
__global__ __launch_bounds__(256) void inorm_stats(
    const float* __restrict__ x, const float* __restrict__ x2,
    float* __restrict__ stats, int HW)
{
    __shared__ float sh[8];
    const int bc = blockIdx.x;
    const float* p  = x + (size_t)bc * HW;
    const float* p2 = x2 ? x2 + (size_t)bc * HW : nullptr;
    float s = 0.f, ss = 0.f;
    for (int i = threadIdx.x; i < HW; i += 256) {
        float v = p[i];
        if (p2) v += p2[i];
        s += v; ss = fmaf(v, v, ss);
    }
#pragma unroll
    for (int o = 32; o; o >>= 1) { s += __shfl_down(s, o); ss += __shfl_down(ss, o); }
    if ((threadIdx.x & 63) == 0) {
        sh[(threadIdx.x >> 6) * 2] = s;
        sh[(threadIdx.x >> 6) * 2 + 1] = ss;
    }
    __syncthreads();
    if (threadIdx.x == 0) {
        s  = sh[0] + sh[2] + sh[4] + sh[6];
        ss = sh[1] + sh[3] + sh[5] + sh[7];
        float m   = s / HW;
        float var = ss / HW - m * m;
        stats[2 * bc]     = m;
        stats[2 * bc + 1] = rsqrtf(var + 1e-5f);
    }
}

// ---------------------------------------------------------------------------
// MFMA deformable conv — 256-thread variant (deform1).
// ---------------------------------------------------------------------------
template <int C, int O, int MF>
__global__ __launch_bounds__(256) void deform_mfma(
    const u16* __restrict__ featT, const float* __restrict__ om,
    const u16* __restrict__ dwt, const float* __restrict__ bias,
    u16* __restrict__ outT, int H, int W, int lgW)
{
    constexpr int NOB = O / 16, NCC = C / 32;
    constexpr int NT = 576;
    constexpr int CPT = C / 4;
    const int HW = H * W;
    const int b  = blockIdx.y;
    const int p0 = blockIdx.x * 64;
    const int tid = threadIdx.x;
    const int wv = tid >> 6, lane = tid & 63, lm = lane & 15, lg = lane >> 4;

    __shared__ int   sO[4][NT];
    __shared__ float sW[4][NT];
    __shared__ u16   val[64 * C];

    for (int t = tid; t < NT; t += 256) {
        int px = t & 63, k = t >> 6;
        int p  = p0 + px;
        int hh = p >> lgW, ww = p & (W - 1);
        float dy = om[((size_t)b * 27 + k) * HW + p];
        float dx = om[((size_t)b * 27 + 9 + k) * HW + p];
        float mk = 1.f / (1.f + __expf(-om[((size_t)b * 27 + 18 + k) * HW + p]));
        float py  = (float)(hh + k / 3 - 1) + dy;
        float pxf = (float)(ww + k % 3 - 1) + dx;
        float y0f = floorf(py), x0f = floorf(pxf);
        int y0 = (int)y0f, x0 = (int)x0f;
        float wy = py - y0f, wx = pxf - x0f;
        float vy0 = ((unsigned)y0       < (unsigned)H) ? 1.f : 0.f;
        float vy1 = ((unsigned)(y0 + 1) < (unsigned)H) ? 1.f : 0.f;
        float vx0 = ((unsigned)x0       < (unsigned)W) ? 1.f : 0.f;
        float vx1 = ((unsigned)(x0 + 1) < (unsigned)W) ? 1.f : 0.f;
        int y0c = min(max(y0, 0), H - 1), y1c = min(max(y0 + 1, 0), H - 1);
        int x0c = min(max(x0, 0), W - 1), x1c = min(max(x0 + 1, 0), W - 1);
        sO[0][t] = y0c * W + x0c;  sO[1][t] = y0c * W + x1c;
        sO[2][t] = y1c * W + x0c;  sO[3][t] = y1c * W + x1c;
        sW[0][t] = (1.f - wy) * (1.f - wx) * vy0 * vx0 * mk;
        sW[1][t] = (1.f - wy) * wx         * vy0 * vx1 * mk;
        sW[2][t] = wy         * (1.f - wx) * vy1 * vx0 * mk;
        sW[3][t] = wy         * wx         * vy1 * vx1 * mk;
    }
    __syncthreads();

    float4v acc[MF][4];
#pragma unroll
    for (int m = 0; m < MF; ++m)
#pragma unroll
        for (int n = 0; n < 4; ++n) acc[m][n] = (float4v){0.f, 0.f, 0.f, 0.f};

    const int gpx = tid >> 2, gc0 = (tid & 3) * CPT;

    for (int k = 0; k < 9; ++k) {
        if (k) __syncthreads();
        {
            int t = k * 64 + gpx;
            int o0 = sO[0][t], o1 = sO[1][t], o2 = sO[2][t], o3 = sO[3][t];
            float w0 = sW[0][t], w1 = sW[1][t], w2 = sW[2][t], w3 = sW[3][t];
#pragma unroll
            for (int c8 = 0; c8 < CPT / 8; ++c8) {
                int c = gc0 + c8 * 8;
                const u16* base = featT + ((size_t)(b * NCC + (c >> 5)) * HW) * 32 + (c & 31);
                uint4 r0 = *(const uint4*)(base + (size_t)o0 * 32);
                uint4 r1 = *(const uint4*)(base + (size_t)o1 * 32);
                uint4 r2 = *(const uint4*)(base + (size_t)o2 * 32);
                uint4 r3 = *(const uint4*)(base + (size_t)o3 * 32);
                const u16* p0_ = (const u16*)&r0;
                const u16* p1_ = (const u16*)&r1;
                const u16* p2_ = (const u16*)&r2;
                const u16* p3_ = (const u16*)&r3;
                u16 outv[8];
#pragma unroll
                for (int j = 0; j < 8; ++j) {
                    float s = w0 * bf2f(p0_[j]) + w1 * bf2f(p1_[j])
                            + w2 * bf2f(p2_[j]) + w3 * bf2f(p3_[j]);
                    outv[j] = f2bf(s);
                }
                int csw = c ^ ((gpx & 7) << 3);
                *(uint4*)(val + gpx * C + csw) = *(uint4*)outv;
            }
        }
        __syncthreads();
        const u16* wk = dwt + (size_t)k * NOB * NCC * 512;
#pragma unroll
        for (int m = 0; m < MF; ++m) {
            int ob = wv * MF + m;
#pragma unroll
            for (int cc = 0; cc < NCC; ++cc) {
                short8 Af = *(const short8*)(wk + ((size_t)ob * NCC + cc) * 512 + lane * 8);
#pragma unroll
                for (int nf = 0; nf < 4; ++nf) {
                    int row = nf * 16 + lm;
                    int csw = (cc * 32 + lg * 8) ^ ((row & 7) << 3);
                    short8 Bf = *(const short8*)(val + row * C + csw);
                    acc[m][nf] = mfma16(Af, Bf, acc[m][nf]);
                }
            }
        }
    }

#pragma unroll
    for (int m = 0; m < MF; ++m) {
        int oc0 = (wv * MF + m) * 16 + lg * 4;
#pragma unroll
        for (int nf = 0; nf < 4; ++nf) {
            int p = p0 + nf * 16 + lm;
#pragma unroll
            for (int r = 0; r < 4; ++r) {
                int oc = oc0 + r;
                outT[((size_t)(b * (O / 32) + (oc >> 5)) * HW + p) * 32 + (oc & 31)]
                    = f2bf(acc[m][nf][r] + bias[oc]);
            }
        }
    }
}

// ---------------------------------------------------------------------------
// 512-thread deformable conv for deform2 (round-16 win).
// ---------------------------------------------------------------------------
template <int C, int O>
__global__ __launch_bounds__(512) void deform_mfma512(
    const u16* __restrict__ featT, const float* __restrict__ om,
    const u16* __restrict__ dwt, const float* __restrict__ bias,
    u16* __restrict__ outT, int H, int W, int lgW)
{
    constexpr int NOB = O / 16, NCC = C / 32;
    constexpr int NT = 576;
    constexpr int CPT = C / 8;
    const int HW = H * W;
    const int b  = blockIdx.y;
    const int p0 = blockIdx.x * 64;
    const int tid = threadIdx.x;
    const int wv = tid >> 6, lane = tid & 63, lm = lane & 15, lg = lane >> 4;

    __shared__ int   sO[4][NT];
    __shared__ float sW[4][NT];
    __shared__ u16   val[64 * C];

    for (int t = tid; t < NT; t += 512) {
        int px = t & 63, k = t >> 6;
        int p  = p0 + px;
        int hh = p >> lgW, ww = p & (W - 1);
        float dy = om[((size_t)b * 27 + k) * HW + p];
        float dx = om[((size_t)b * 27 + 9 + k) * HW + p];
        float mk = 1.f / (1.f + __expf(-om[((size_t)b * 27 + 18 + k) * HW + p]));
        float py  = (float)(hh + k / 3 - 1) + dy;
        float pxf = (float)(ww + k % 3 - 1) + dx;
        float y0f = floorf(py), x0f = floorf(pxf);
        int y0 = (int)y0f, x0 = (int)x0f;
        float wy = py - y0f, wx = pxf - x0f;
        float vy0 = ((unsigned)y0       < (unsigned)H) ? 1.f : 0.f;
        float vy1 = ((unsigned)(y0 + 1) < (unsigned)H) ? 1.f : 0.f;
        float vx0 = ((unsigned)x0       < (unsigned)W) ? 1.f : 0.f;
        float vx1 = ((unsigned)(x0 + 1) < (unsigned)W) ? 1.f : 0.f;
        int y0c = min(max(y0, 0), H - 1), y1c = min(max(y0 + 1, 0), H - 1);
        int x0c = min(max(x0, 0), W - 1), x1c = min(max(x0 + 1, 0), W - 1);
        sO[0][t] = y0c * W + x0c;  sO[1][t] = y0c * W + x1c;
        sO[2][t] = y1c * W + x0c;  sO[3][t] = y1c * W + x1c;
        sW[0][t] = (1.f - wy) * (1.f - wx) * vy0 * vx0 * mk;
        sW[1][t] = (1.f - wy) * wx         * vy0 * vx1 * mk;
        sW[2][t] = wy         * (1.f - wx) * vy1 * vx0 * mk;
        sW[3][t] = wy         * wx         * vy1 * vx1 * mk;
    }
    __syncthreads();

    float4v acc[4];
#pragma unroll
    for (int n = 0; n < 4; ++n) acc[n] = (float4v){0.f, 0.f, 0.f, 0.f};

    const int gpx = tid >> 3, gc0 = (tid & 7) * CPT;

    for (int k = 0; k < 9; ++k) {
        if (k) __syncthreads();
        {
            int t = k * 64 + gpx;
            int o0 = sO[0][t], o1 = sO[1][t], o2 = sO[2][t], o3 = sO[3][t];
            float w0 = sW[0][t], w1 = sW[1][t], w2 = sW[2][t], w3 = sW[3][t];
#pragma unroll
            for (int c8 = 0; c8 < CPT / 8; ++c8) {
                int c = gc0 + c8 * 8;
                const u16* base = featT + ((size_t)(b * NCC + (c >> 5)) * HW) * 32 + (c & 31);
                uint4 r0 = *(const uint4*)(base + (size_t)o0 * 32);
                uint4 r1 = *(const uint4*)(base + (size_t)o1 * 32);
                uint4 r2 = *(const uint4*)(base + (size_t)o2 * 32);
                uint4 r3 = *(const uint4*)(base + (size_t)o3 * 32);
                const u16* p0_ = (const u16*)&r0;
                const u16* p1_ = (const u16*)&r1;
                const u16* p2_ = (const u16*)&r2;
                const u16* p3_ = (const u16*)&r3;
                u16 outv[8];
#pragma unroll
                for (int j = 0; j < 8; ++j) {
                    float s = w0 * bf2f(p0_[j]) + w1 * bf2f(p1_[j])
                            + w2 * bf2f(p2_[j]) + w3 * bf2f(p3_[j]);
                    outv[j] = f2bf(s);
                }
                int csw = c ^ ((gpx & 7) << 3);
                *(uint4*)(val + gpx * C + csw) = *(uint4*)outv;
            }
        }
        __syncthreads();
        const u16* wk = dwt + (size_t)k * NOB * NCC * 512;
        const int ob = wv;
#pragma unroll
        for (int cc = 0; cc < NCC; ++cc) {
            short8 Af = *(const short8*)(wk + ((size_t)ob * NCC + cc) * 512 + lane * 8);
#pragma unroll
            for (int nf = 0; nf < 4; ++nf) {
                int row = nf * 16 + lm;
                int csw = (cc * 32 + lg * 8) ^ ((row & 7) << 3);
                short8 Bf = *(const short8*)(val + row * C + csw);
                acc[nf] = mfma16(Af, Bf, acc[nf]);
            }
        }
    }

    {
        int oc0 = wv * 16 + lg * 4;
#pragma unroll
        for (int nf = 0; nf < 4; ++nf) {
            int p = p0 + nf * 16 + lm;
#pragma unroll
            for (int r = 0; r < 4; ++r) {
                int oc = oc0 + r;
                outT[((size_t)(b * (O / 32) + (oc >> 5)) * HW + p) * 32 + (oc & 31)]
                    = f2bf(acc[nf][r] + bias[oc]);
            }
        }
    }
}

// ---------------------- c3 K-split combine: out = tanh(PA + PB) -----------
__global__ __launch_bounds__(256) void combine_tanh(
    float* __restrict__ out, const float* __restrict__ pb, int n)
{
    int i = blockIdx.x * 256 + threadIdx.x;
    if (i < n) out[i] = tanhf(out[i] + pb[i]);
}

// ---------------------- offset |mean| reductions --------------------------
__global__ __launch_bounds__(256) void absmean_partial(
    const float* __restrict__ om, int HW, float* __restrict__ partial)
{
    const int n18 = 18 * HW;
    const long long total = 4LL * n18;
    float s = 0.f;
    for (long long i = (long long)blockIdx.x * 256 + threadIdx.x; i < total;
         i += (long long)gridDim.x * 256) {
        int b = (int)(i / n18);
        int r = (int)(i % n18);
        s += fabsf(om[(size_t)b * 27 * HW + r]);
    }
    __shared__ float sh[4];
#pragma unroll
    for (int o = 32; o; o >>= 1) s += __shfl_down(s, o);
    if ((threadIdx.x & 63) == 0) sh[threadIdx.x >> 6] = s;
    __syncthreads();
    if (threadIdx.x == 0) partial[blockIdx.x] = sh[0] + sh[1] + sh[2] + sh[3];
}

__global__ __launch_bounds__(256) void finalize_k(
    const float* __restrict__ p1, const float* __restrict__ p2,
    float* __restrict__ outScalar)
{
    __shared__ float sh[8];
    float a = p1[threadIdx.x] + p1[threadIdx.x + 256];
    float b = p2[threadIdx.x] + p2[threadIdx.x + 256];
#pragma unroll
    for (int o = 32; o; o >>= 1) { a += __shfl_down(a, o); b += __shfl_down(b, o); }
    if ((threadIdx.x & 63) == 0) {
        sh[(threadIdx.x >> 6) * 2]     = a;
        sh[(threadIdx.x >> 6) * 2 + 1] = b;
    }
    __syncthreads();
    if (threadIdx.x == 0) {
        a = sh[0] + sh[2] + sh[4] + sh[6];
        b = sh[1] + sh[3] + sh[5] + sh[7];
        *outScalar = 0.5f * (a / (4.f * 18.f * 16384.f) + b / (4.f * 18.f * 4096.f));
    }
}

// ---------------------------------------------------------------------------
extern "C" void kernel_launch(void* const* d_in, const int* in_sizes, int n_in,
                              void* d_out, int out_size, void* d_ws, size_t ws_size,
                              hipStream_t stream)
{
    const float* x      = (const float*)d_in[0];
    const float* skip1  = (const float*)d_in[1];
    const float* skip2  = (const float*)d_in[2];
    const float* rb1_w1 = (const float*)d_in[3];
    const float* rb1_b1 = (const float*)d_in[4];
    const float* rb1_w2 = (const float*)d_in[5];
    const float* rb1_b2 = (const float*)d_in[6];
    const float* rb2_w1 = (const float*)d_in[7];
    const float* rb2_b1 = (const float*)d_in[8];
    const float* rb2_w2 = (const float*)d_in[9];
    const float* rb2_b2 = (const float*)d_in[10];
    const float* c1_w   = (const float*)d_in[11];
    const float* c1_b   = (const float*)d_in[12];
    const float* c2_w   = (const float*)d_in[13];
    const float* c2_b   = (const float*)d_in[14];
    const float* c3_w   = (const float*)d_in[15];
    const float* c3_b   = (const float*)d_in[16];
    const float* off2_w = (const float*)d_in[17];
    const float* off2_b = (const float*)d_in[18];
    const float* d2_w   = (const float*)d_in[19];
    const float* d2_b   = (const float*)d_in[20];
    const float* off1_w = (const float*)d_in[21];
    const float* off1_b = (const float*)d_in[22];
    const float* d1_w   = (const float*)d_in[23];
    const float* d1_b   = (const float*)d_in[24];

    float* ws    = (float*)d_ws;
    float* stats = ws;
    float* part2 = ws + 2048;
    float* part1 = ws + 2560;

    // ---- weight pack arenas (words) ----
    u16* wtRB1 = (u16*)(ws + 4096);
    u16* wtC1 = (u16*)(ws + 299008);
    u16* wtC2 = (u16*)(ws + 708608);
    u16* wtO2 = (u16*)(ws + 913408);
    u16* wtO1 = (u16*)(ws + 950272);
    u16* wtC3 = (u16*)(ws + 968704);
    // ---- Z1 @1018880: R2 fp32 (4M w) with early overlays ----
    float* R2  = ws + 1018880;                 // [c2 -> pack32]
    u16*  xT   = (u16*)(ws + 1018880);
    u16*  A1T  = xT;
    u16*  A2T  = (u16*)(ws + 1018880 + 524288);
    u16*  A3T  = A2T;
    float* A1  = ws + 1018880 + 1048576;
    float* A2  = ws + 1018880 + 2097152;
    float* A3  = ws + 1018880 + 3145728;       // rb K-split partial (PB)
    float* OM2 = ws + 1018880;                 // [off2 -> deform2/absmean]
    u16*  CP1T = (u16*)(ws + 1018880);         // [deform1 -> c3] (OM2/R2 dead)
    float* PBC1 = ws + 1018880 + 1048576;      // c1 K-split partial (A1+A2 zones)
    // ---- Z2: s1T @5213184 ----
    u16*  s1T  = (u16*)(ws + 5213184);         // [-> deform1]
    // ---- Z3 @7310336 (2M w): rb2-4 weight arenas UPFRONT, dead before c1
    u16*  wtRB2 = (u16*)(ws + 7310336);        // 294912 w [upfront -> rb1c2]
    u16*  wtRB3 = (u16*)(ws + 7605248);        // 294912 w [upfront -> rb2c1]
    u16*  wtRB4 = (u16*)(ws + 7900160);        // 294912 w [upfront -> rb2c2]
    float* R1  = ws + 7310336;                 // [c1 -> pack32]
    u16*  CP2T = (u16*)(ws + 7384064);         // [deform2 -> c2]
    u16*  R2T  = (u16*)(ws + 7310336);         // [pack32(after c2) -> off1, c3]
    // ---- Z4 @9407488: R1T then OM1 ----
    u16*  R1T  = (u16*)(ws + 9407488);         // [-> c2]
    float* OM1 = ws + 9407488;                 // [off1 -> deform1/absmean]
    // ---- Z5: s2T @10456064 (ends 11504640) ----
    u16*  s2T  = (u16*)(ws + 10456064);        // [-> deform2]
    // ---- tail @11504640: deform weight arenas (word-sized, round-19 fix),
    //      then c3 K-split partial. End 11793408 w = 47.2 MB (<= 48.7 proven).
    u16*  wtD2 = (u16*)(ws + 11504640);        // 73728 w [upfront -> deform2]
    u16*  wtD1 = (u16*)(ws + 11578368);        // 18432 w [upfront -> deform1]
    float* PBC3 = ws + 11596800;               // 196608 w [c3 -> combine]

    float* outp = (float*)d_out;
    dim3 blk(256);

    // ---- batched weight packs + deform packs: all upfront ----
    WSegs segs;
    segs.w[0] = c1_w;   segs.dst[0] = wtC1;  segs.OC[0] = 128; segs.IC[0] = 256; segs.K2[0] = 25; segs.NOB[0] = 8;  segs.total[0] = 819200;
    segs.w[1] = c2_w;   segs.dst[1] = wtC2;  segs.OC[1] = 64;  segs.IC[1] = 256; segs.K2[1] = 25; segs.NOB[1] = 4;  segs.total[1] = 409600;
    segs.w[2] = off2_w; segs.dst[2] = wtO2;  segs.OC[2] = 27;  segs.IC[2] = 256; segs.K2[2] = 9;  segs.NOB[2] = 2;  segs.total[2] = 73728;
    segs.w[3] = off1_w; segs.dst[3] = wtO1;  segs.OC[3] = 27;  segs.IC[3] = 128; segs.K2[3] = 9;  segs.NOB[3] = 2;  segs.total[3] = 36864;
    segs.w[4] = c3_w;   segs.dst[4] = wtC3;  segs.OC[4] = 3;   segs.IC[4] = 128; segs.K2[4] = 49; segs.NOB[4] = 1;  segs.total[4] = 100352;
    segs.w[5] = rb1_w1; segs.dst[5] = wtRB1; segs.OC[5] = 256; segs.IC[5] = 256; segs.K2[5] = 9;  segs.NOB[5] = 16; segs.total[5] = 589824;
    segs.w[6] = rb1_w2; segs.dst[6] = wtRB2; segs.OC[6] = 256; segs.IC[6] = 256; segs.K2[6] = 9;  segs.NOB[6] = 16; segs.total[6] = 589824;
    segs.w[7] = rb2_w1; segs.dst[7] = wtRB3; segs.OC[7] = 256; segs.IC[7] = 256; segs.K2[7] = 9;  segs.NOB[7] = 16; segs.total[7] = 589824;
    segs.w[8] = rb2_w2; segs.dst[8] = wtRB4; segs.OC[8] = 256; segs.IC[8] = 256; segs.K2[8] = 9;  segs.NOB[8] = 16; segs.total[8] = 589824;
    wpack_batch<<<dim3(3200, 9), blk, 0, stream>>>(segs);
    dwtrans<128, 128><<<576, blk, 0, stream>>>(d2_w, wtD2);
    dwtrans<64, 64><<<144, blk, 0, stream>>>(d1_w, wtD1);

    // ---- input transforms ----
    pack32<0, false, false, 6><<<dim3(16, 8, 4), blk, 0, stream>>>(x, nullptr, nullptr, nullptr, nullptr, xT, 10, 8);
    pack32<0, false><<<dim3(64, 2, 4), blk, 0, stream>>>(skip1, nullptr, nullptr, nullptr, nullptr, s1T, 14, 6);
    pack32<0, false, false, 6><<<dim3(64, 4, 4), blk, 0, stream>>>(skip2, nullptr, nullptr, nullptr, nullptr, s2T, 12, 7);

    // ---- resblock 1 conv 1 (KSPLIT=2: PA=A1+bias, PB=A3) ----
    mconv<3, false, true, 2, 5, 4, 0, 1, 2><<<dim3(8, 8, 8), blk, 32768, stream>>>(
        xT, 8, nullptr, 8, wtRB1, 16, rb1_b1, A1, 256, 32, 32, 1, 32, A3);
    inorm_stats<<<1024, blk, 0, stream>>>(A1, A3, stats, 1024);
    pack32<1, false, true, 6><<<dim3(16, 8, 4), blk, 0, stream>>>(A1, A3, nullptr, stats, nullptr, A1T, 10, 8);
    // ---- resblock 1 conv 2 ----
    mconv<3, false, true, 2, 5, 4, 0, 1, 2><<<dim3(8, 8, 8), blk, 32768, stream>>>(
        A1T, 8, nullptr, 8, wtRB2, 16, rb1_b2, A2, 256, 32, 32, 1, 32, A3);
    inorm_stats<<<1024, blk, 0, stream>>>(A2, A3, stats, 1024);
    pack32<2, true, true, 6><<<dim3(16, 8, 4), blk, 0, stream>>>(A2, A3, A2, stats, x, A2T, 10, 8);
    // ---- resblock 2 conv 1 ----
    mconv<3, false, true, 2, 5, 4, 0, 1, 2><<<dim3(8, 8, 8), blk, 32768, stream>>>(
        A2T, 8, nullptr, 8, wtRB3, 16, rb2_b1, A1, 256, 32, 32, 1, 32, A3);
    inorm_stats<<<1024, blk, 0, stream>>>(A1, A3, stats, 1024);
    pack32<1, false, true, 6><<<dim3(16, 8, 4), blk, 0, stream>>>(A1, A3, nullptr, stats, nullptr, A1T, 10, 8);
    // ---- resblock 2 conv 2 ----
    mconv<3, false, true, 2, 5, 4, 0, 1, 2><<<dim3(8, 8, 8), blk, 32768, stream>>>(
        A1T, 8, nullptr, 8, wtRB4, 16, rb2_b2, A3, 256, 32, 32, 1, 32, A1);
    inorm_stats<<<1024, blk, 0, stream>>>(A3, A1, stats, 1024);
    pack32<2, false, true, 6><<<dim3(16, 8, 4), blk, 0, stream>>>(A3, A1, nullptr, stats, A2, A3T, 10, 8);
    // ---- c1: up2 + 5x5 reflect, 256->128 @64 (MF=2 + KSPLIT=2) ----
    mconv<5, true, true, 2, 6, 2, 0, 2, 2><<<dim3(32, 2, 8), blk, 57344, stream>>>(
        A3T, 8, nullptr, 8, wtC1, 8, c1_b, R1, 128, 64, 64, 1, 32, PBC1);
    inorm_stats<<<512, blk, 0, stream>>>(R1, PBC1, stats, 4096);
    pack32<1, false, true, 6><<<dim3(64, 4, 4), blk, 0, stream>>>(R1, PBC1, nullptr, stats, nullptr, R1T, 12, 7);
    // ---- off2 -> deform2 (absmean off critical path) ----
    mconv<3, false, false, 2, 6, 2><<<dim3(32, 1, 4), blk, 40960, stream>>>(
        R1T, 4, s2T, 8, wtO2, 2, off2_b, OM2, 27, 64, 64, 1, 64);
    deform_mfma512<128, 128><<<dim3(64, 4), dim3(512), 0, stream>>>(
        s2T, OM2, wtD2, d2_b, CP2T, 64, 64, 6);
    absmean_partial<<<512, blk, 0, stream>>>(OM2, 4096, part2);
    // ---- c2: up2(concat(CP2T, R1T)) + 5x5 reflect (round-11 proven) ----
    mconv<5, true, true, 2, 6, 2, 0, 2><<<dim3(128, 1, 4), blk, 57344, stream>>>(
        CP2T, 4, R1T, 8, wtC2, 4, c2_b, R2, 64, 128, 128, 2, 64);
    inorm_stats<<<256, blk, 0, stream>>>(R2, nullptr, stats, 16384);
    pack32<1, false><<<dim3(64, 2, 4), blk, 0, stream>>>(R2, nullptr, nullptr, stats, nullptr, R2T, 14, 6);
    // ---- off1 -> deform1 ----
    mconv<3, false, false, 2, 6, 2><<<dim3(128, 1, 4), blk, 40960, stream>>>(
        R2T, 2, s1T, 4, wtO1, 2, off1_b, OM1, 27, 128, 128, 2, 128);
    deform_mfma<64, 64, 1><<<dim3(256, 4), blk, 0, stream>>>(
        s1T, OM1, wtD1, d1_b, CP1T, 128, 128, 7);
    absmean_partial<<<512, blk, 0, stream>>>(OM1, 16384, part1);
    // ---- c3: concat(CP1T, R2T) 7x7 reflect -> 3ch, KSPLIT=2 (512 blocks,
    //      2/CU vs 1/CU before); tanh moves to combine_tanh ----
    mconv<7, false, true, 1, 4, 16, 0, 1, 2><<<dim3(64, 1, 8), blk, 65536, stream>>>(
        CP1T, 2, R2T, 4, wtC3, 1, c3_b, outp, 3, 128, 128, 8, 128, PBC3);
    combine_tanh<<<768, blk, 0, stream>>>(outp, PBC3, 196608);
    // ---- offset_sum ----
    finalize_k<<<1, blk, 0, stream>>>(part1, part2, outp + 196608);
}